// Round 8
// baseline (220.335 us; speedup 1.0000x reference)
//
#include <hip/hip_runtime.h>

// Planar NF v7: v6 math (MFMA bf16 hi/lo 3-pass), restructured for occupancy.
//  nf_gen (1 block, unchanged/proven): W hi/lo bf16 [32][264], Uhat^T hi/lo
//    bf16 [256][40], G fp32 [32][32], c fp32 -> workspace.
//  nf_fused: 1024 blocks x 512 thr (8 waves), ROWS=64, LDS 51200 B -> 3 blk/CU,
//    __launch_bounds__(512,6) caps VGPR ~84 -> 24 waves/CU (vs v6's 8).
//    Region A (40960B): W hi/lo (phase1) -> P fp32 [32][65] -> Uhat^T hi/lo.
//    Region B (10240B): X-chunk / T, bf16 hi/lo [64][40].
//    G/c/b are read via wave-uniform s_load from ws (no LDS staging).

typedef __attribute__((ext_vector_type(8))) short short8;
typedef __attribute__((ext_vector_type(4))) float f32x4;

#define B_ 65536
#define D_ 256
#define ROWS 64
#define NTHR 512
#define GRID (B_ / ROWS)

// workspace byte offsets (same as v6)
#define WSB_WH 0       // W hi bf16 [32][264]
#define WSB_WL 16896   // W lo
#define WSB_UTH 33792  // Uhat^T hi bf16 [256][40]
#define WSB_UTL 54272  // Uhat^T lo
#define WSB_G 74752    // G fp32 [32][32]
#define WSB_C 78848    // c fp32 [32]

// lds half-offsets
#define WH_H 0      // region A: W hi [32][264]
#define WL_H 8448   //           W lo
#define UH_H 0      //           (phase3 overlay) U^T hi [256][40]
#define UL_H 10240  //           U^T lo
#define XH_H 20480  // region B: X-chunk / T hi [64][40]
#define XL_H 23040  //           lo
#define LDS_HALVES 25600  // 51200 B
// region A float view: P [32][65] fp32 at float offset 0 (<= 10240 floats)
#define P_STR 65

__device__ __forceinline__ void bfsplit(float x, unsigned short& h, unsigned short& l) {
  unsigned xb = __float_as_uint(x) & 0xffff0000u;
  h = (unsigned short)(xb >> 16);
  float r = x - __uint_as_float(xb);
  l = (unsigned short)(__float_as_uint(r) >> 16);
}

__global__ __launch_bounds__(256) void nf_gen(const float* __restrict__ u_in,
                                              const float* __restrict__ w_in,
                                              float* __restrict__ ws) {
  __shared__ float wTg[8192];  // [d][k]
  __shared__ float ug[8192];   // [j][d]
  __shared__ float wu_s[32], ww_s[32], coefs_s[32];
  const int t = threadIdx.x;
  {
    const int k = t & 31, d0 = (t >> 5) * 32;
    const float4* wp = (const float4*)(w_in + k * 256 + d0);
#pragma unroll
    for (int q = 0; q < 8; ++q) {
      float4 v = wp[q];
      wTg[(d0 + q * 4 + 0) * 32 + k] = v.x;
      wTg[(d0 + q * 4 + 1) * 32 + k] = v.y;
      wTg[(d0 + q * 4 + 2) * 32 + k] = v.z;
      wTg[(d0 + q * 4 + 3) * 32 + k] = v.w;
    }
#pragma unroll
    for (int q = 0; q < 8; ++q)
      ((float4*)ug)[t + 256 * q] = ((const float4*)u_in)[t + 256 * q];
  }
  __syncthreads();
  const int k = t & 31, jg = t >> 5;  // row k, cols jg*4..+4
  float m1[4] = {0.f, 0.f, 0.f, 0.f}, m2[4] = {0.f, 0.f, 0.f, 0.f};
#pragma unroll 4
  for (int dc = 0; dc < 64; ++dc) {
    float wk[4];
    float4 wj[4], uj[4];
#pragma unroll
    for (int i = 0; i < 4; ++i) wk[i] = wTg[(dc * 4 + i) * 32 + k];
#pragma unroll
    for (int i = 0; i < 4; ++i) wj[i] = *(const float4*)&wTg[(dc * 4 + i) * 32 + jg * 4];
#pragma unroll
    for (int i = 0; i < 4; ++i) uj[i] = *(const float4*)&ug[(jg * 4 + i) * 256 + dc * 4];
#pragma unroll
    for (int i = 0; i < 4; ++i) {
      m1[i] = fmaf(uj[i].x, wk[0], m1[i]);
      m1[i] = fmaf(uj[i].y, wk[1], m1[i]);
      m1[i] = fmaf(uj[i].z, wk[2], m1[i]);
      m1[i] = fmaf(uj[i].w, wk[3], m1[i]);
    }
    const float* w0 = (const float*)&wj[0];
    const float* w1 = (const float*)&wj[1];
    const float* w2 = (const float*)&wj[2];
    const float* w3 = (const float*)&wj[3];
#pragma unroll
    for (int i = 0; i < 4; ++i) {
      m2[i] = fmaf(w0[i], wk[0], m2[i]);
      m2[i] = fmaf(w1[i], wk[1], m2[i]);
      m2[i] = fmaf(w2[i], wk[2], m2[i]);
      m2[i] = fmaf(w3[i], wk[3], m2[i]);
    }
  }
  if ((k >> 2) == jg) {  // holds diagonal j==k
    wu_s[k] = m1[k & 3];
    ww_s[k] = m2[k & 3];
  }
  __syncthreads();
  if (t < 32) {
    float wu = wu_s[t], ww = ww_s[t];
    float sp = fmaxf(wu, 0.f) + log1pf(__expf(-fabsf(wu)));
    coefs_s[t] = (sp - 1.f - wu) / ww;
    ((float*)((char*)ws + WSB_C))[t] = sp - 1.f;  // c_k
  }
  __syncthreads();
  {
    float* gws = (float*)((char*)ws + WSB_G);
#pragma unroll
    for (int i = 0; i < 4; ++i)
      gws[k * 32 + jg * 4 + i] = fmaf(coefs_s[jg * 4 + i], m2[i], m1[i]);
  }
  // bf16 hi/lo outputs: W [32][264], Uhat^T [256][40]
  {
    const int k2 = t >> 3, d0 = (t & 7) * 32;
    const float ck = coefs_s[k2];
    unsigned short* whp = (unsigned short*)((char*)ws + WSB_WH);
    unsigned short* wlp = (unsigned short*)((char*)ws + WSB_WL);
    unsigned short* uthp = (unsigned short*)((char*)ws + WSB_UTH);
    unsigned short* utlp = (unsigned short*)((char*)ws + WSB_UTL);
    const float4* wp2 = (const float4*)(w_in + k2 * 256 + d0);
    const float4* up2 = (const float4*)(u_in + k2 * 256 + d0);
#pragma unroll
    for (int q = 0; q < 8; ++q) {
      float4 wv = wp2[q], uv = up2[q];
      const float wf[4] = {wv.x, wv.y, wv.z, wv.w};
      const float uf[4] = {uv.x, uv.y, uv.z, uv.w};
#pragma unroll
      for (int i = 0; i < 4; ++i) {
        unsigned short hh, ll;
        bfsplit(wf[i], hh, ll);
        whp[k2 * 264 + d0 + q * 4 + i] = hh;
        wlp[k2 * 264 + d0 + q * 4 + i] = ll;
        float uhv = fmaf(ck, wf[i], uf[i]);
        bfsplit(uhv, hh, ll);
        uthp[(d0 + q * 4 + i) * 40 + k2] = hh;
        utlp[(d0 + q * 4 + i) * 40 + k2] = ll;
      }
    }
  }
}

__global__ __launch_bounds__(NTHR, 6) void nf_fused(const float* __restrict__ X,
                                                    const float* __restrict__ b_in,
                                                    const float* __restrict__ ws,
                                                    float* __restrict__ out) {
  __shared__ __align__(16) unsigned short ldsH[LDS_HALVES];
  float* ldsF = (float*)ldsH;

  const int t = threadIdx.x;
  const int lane = t & 63;
  const int wv = t >> 6;       // wave 0..7
  const int ln15 = lane & 15;
  const int g = lane >> 4;     // 0..3
  const int g8 = g * 8, g4 = g * 4;
  const int slab = wv >> 1;    // M-slab 0..3 (16 rows)
  const int nt0 = wv & 1;      // N parity
  const int row0 = blockIdx.x * ROWS;

  // stage W hi/lo bf16 into region A (33792 B = 2112 uint4)
  {
    const uint4* wsrc = (const uint4*)((const char*)ws + WSB_WH);
    uint4* wdst = (uint4*)ldsH;
#pragma unroll
    for (int i = 0; i < 4; ++i) wdst[t + 512 * i] = wsrc[t + 512 * i];
    if (t < 64) wdst[2048 + t] = wsrc[2048 + t];
  }

  // phase-1 X chunk staging: thread -> (srow, 4 d)
  const int srow = t >> 3;
  const int sd = (t & 7) * 4;
  float4 xr;
  auto load_stage = [&](int cc) {
    xr = *(const float4*)(X + (size_t)(row0 + srow) * 256 + cc * 32 + sd);
  };
  auto store_stage = [&]() {
    const float xf[4] = {xr.x, xr.y, xr.z, xr.w};
    unsigned short h[4], l[4];
#pragma unroll
    for (int e = 0; e < 4; ++e) bfsplit(xf[e], h[e], l[e]);
    *(uint2*)&ldsH[XH_H + srow * 40 + sd] =
        make_uint2((unsigned)h[0] | ((unsigned)h[1] << 16),
                   (unsigned)h[2] | ((unsigned)h[3] << 16));
    *(uint2*)&ldsH[XL_H + srow * 40 + sd] =
        make_uint2((unsigned)l[0] | ((unsigned)l[1] << 16),
                   (unsigned)l[2] | ((unsigned)l[3] << 16));
  };

  // ---------------- phase 1: P = X . W^T (MFMA, wave = slab x N-tile) -------
  f32x4 acc = (f32x4){0.f, 0.f, 0.f, 0.f};
  load_stage(0);
  for (int cc = 0; cc < 8; ++cc) {
    store_stage();
    __syncthreads();  // (first iter: also covers W staging)
    if (cc < 7) load_stage(cc + 1);
    const int hidx = XH_H + (slab * 16 + ln15) * 40 + g8;
    short8 ah = *(const short8*)&ldsH[hidx];
    short8 al = *(const short8*)&ldsH[hidx + (XL_H - XH_H)];
    const int widx = (nt0 * 16 + ln15) * 264 + cc * 32 + g8;
    short8 bh = *(const short8*)&ldsH[WH_H + widx];
    short8 bl = *(const short8*)&ldsH[WL_H + widx];
    acc = __builtin_amdgcn_mfma_f32_16x16x32_bf16(ah, bh, acc, 0, 0, 0);
    acc = __builtin_amdgcn_mfma_f32_16x16x32_bf16(ah, bl, acc, 0, 0, 0);
    acc = __builtin_amdgcn_mfma_f32_16x16x32_bf16(al, bh, acc, 0, 0, 0);
    __syncthreads();
  }

  // ---------------- P dump fp32 [32 k][65 r] over dead W region -------------
  {
    const int kcol = nt0 * 16 + ln15;
#pragma unroll
    for (int q = 0; q < 4; ++q)
      ldsF[kcol * P_STR + slab * 16 + g4 + q] = acc[q];
  }
  __syncthreads();

  // ---------------- recurrence: one row per thread (t < 64), lean VGPR ------
  if (t < 64) {
    const float* gws = (const float*)((const char*)ws + WSB_G);
    const float* cws = (const float*)((const char*)ws + WSB_C);
    float tvv[32];
#pragma unroll
    for (int kk = 0; kk < 32; ++kk) {
      float la = ldsF[kk * P_STR + t] + b_in[kk];
      float lb2 = 0.f;
      const float* gp = gws + kk * 32;  // uniform -> s_load
#pragma unroll
      for (int j = 0; j + 1 < kk; j += 2) {
        la = fmaf(tvv[j], gp[j], la);
        lb2 = fmaf(tvv[j + 1], gp[j + 1], lb2);
      }
      if (kk & 1) la = fmaf(tvv[kk - 1], gp[kk - 1], la);
      float lin = la + lb2;
      float e = __expf(2.f * lin);
      float tk = 1.f - 2.f / (e + 1.f);
      tvv[kk] = tk;
      unsigned short hh, ll;
      bfsplit(tk, hh, ll);
      ldsH[XH_H + t * 40 + kk] = hh;  // T hi/lo [r][40] over dead X region
      ldsH[XL_H + t * 40 + kk] = ll;
      float val = fabsf(fmaf(1.f - tk * tk, cws[kk], 1.f)) + 1e-8f;
      out[(size_t)B_ * D_ + (size_t)kk * B_ + row0 + t] = __logf(val);
    }
  }
  __syncthreads();

  // ---------------- stage Uhat^T hi/lo over dead W+P region (40960 B) ------
  {
    const uint4* usrc = (const uint4*)((const char*)ws + WSB_UTH);
    uint4* udst = (uint4*)ldsH;
#pragma unroll
    for (int i = 0; i < 5; ++i) udst[t + 512 * i] = usrc[t + 512 * i];
  }
  __syncthreads();

  // ---------------- phase 3: Z = X + T . Uhat (MFMA, X via C operand) -------
  {
    const int hidx = XH_H + (slab * 16 + ln15) * 40 + g8;
    short8 tah = *(const short8*)&ldsH[hidx];
    short8 tal = *(const short8*)&ldsH[hidx + (XL_H - XH_H)];
    const size_t rbase = (size_t)row0 + slab * 16 + g4;
#pragma unroll 2
    for (int i = 0; i < 8; ++i) {
      const int nt = nt0 + 2 * i;
      const int uidx = (nt * 16 + ln15) * 40 + g8;
      short8 bh = *(const short8*)&ldsH[UH_H + uidx];
      short8 bl = *(const short8*)&ldsH[UL_H + uidx];
      const int col = nt * 16 + ln15;
      f32x4 c;
#pragma unroll
      for (int q = 0; q < 4; ++q) c[q] = X[(rbase + q) * 256 + col];
      c = __builtin_amdgcn_mfma_f32_16x16x32_bf16(tah, bh, c, 0, 0, 0);
      c = __builtin_amdgcn_mfma_f32_16x16x32_bf16(tah, bl, c, 0, 0, 0);
      c = __builtin_amdgcn_mfma_f32_16x16x32_bf16(tal, bh, c, 0, 0, 0);
#pragma unroll
      for (int q = 0; q < 4; ++q) out[(rbase + q) * 256 + col] = c[q];
    }
  }
}

extern "C" void kernel_launch(void* const* d_in, const int* in_sizes, int n_in,
                              void* d_out, int out_size, void* d_ws, size_t ws_size,
                              hipStream_t stream) {
  const float* X = (const float*)d_in[0];
  // d_in[1] = h : unused by the math
  const float* u = (const float*)d_in[2];
  const float* w = (const float*)d_in[3];
  const float* b = (const float*)d_in[4];
  float* out = (float*)d_out;
  float* ws = (float*)d_ws;

  nf_gen<<<1, 256, 0, stream>>>(u, w, ws);
  nf_fused<<<GRID, NTHR, 0, stream>>>(X, b, ws, out);
}